// Round 6
// baseline (183.058 us; speedup 1.0000x reference)
//
#include <hip/hip_runtime.h>
#include <hip/hip_bf16.h>
#include <math.h>

// MoE top-2 of 8 experts. B=8, C=512, HW=1024, Dh=1024, E=8. fp32 in/out.
// R6: L2-traffic-driven retile. gemm1 256x256/BK32, 512thr, grid 256 (1 blk/CU);
// gemm2 128x128/BK64, grid 256. Staged-bytes-per-output halved; one block per
// CU removes 4-way L2-port contention seen in R5 (1687 cyc/iter for 16KB+64 MFMA).
// Workspace (byte offsets):
//   0      tidx int[16]
//   64     scale fp32[16]
//   32768  xT  bf16 [8][1024 hw][512 c]
//   +8M    W1t bf16 [8][1024 d][512 c]
//   +16M   W2t bf16 [8][512 c][1024 d]
//   +24M   hT  bf16 [8][1024 hw][2048 slotd]  (pp fp32[8][16][512] aliases hT;
//                                              consumed by gate before gemm1)

typedef __bf16 bf16_t;
typedef __attribute__((ext_vector_type(8))) __bf16 bf16x8;
typedef __attribute__((ext_vector_type(4))) __bf16 bf16x4;
typedef __attribute__((ext_vector_type(4))) float f32x4;

#define GLDS(g, l) __builtin_amdgcn_global_load_lds(                      \
    (const __attribute__((address_space(1))) void*)(const void*)(g),       \
    (__attribute__((address_space(3))) void*)(void*)(l), 16, 0, 0)

// erf via Abramowitz-Stegun 7.1.26 (validated R2..R5, absmax 0.031)
__device__ __forceinline__ float gelu_fast(float x) {
    float z = x * 0.70710678118654752f;
    float az = fabsf(z);
    float t = 1.0f / (1.0f + 0.3275911f * az);
    float p = ((((1.061405429f * t - 1.453152027f) * t + 1.421413741f) * t
                - 0.284496736f) * t + 0.254829592f) * t;
    float e = __expf(-az * az);
    float er = copysignf(1.0f - p * e, z);
    return 0.5f * x * (1.0f + er);
}

// ---------- 1. coalesced 64x64 transpose+cvt for x/W1/W2 + gate partials ----------
__global__ __launch_bounds__(256) void transpose_cvt_all(
    const float* __restrict__ x, const float* __restrict__ W1,
    const float* __restrict__ W2, bf16_t* __restrict__ xT,
    bf16_t* __restrict__ W1t, bf16_t* __restrict__ W2t, float* __restrict__ pp) {
    int id = blockIdx.x;
    const float* src; bf16_t* dst; int Rows, Cols, csh; bool dm = false;
    if (id < 1024)      { src = x;  dst = xT;  Rows = 512;  Cols = 1024; csh = 4; dm = true; }
    else if (id < 2048) { id -= 1024; src = W1; dst = W1t; Rows = 512;  Cols = 1024; csh = 4; }
    else                { id -= 2048; src = W2; dst = W2t; Rows = 1024; Cols = 512; csh = 3; }
    const int bz = id >> 7, t = id & 127;
    const int ct = t & ((1 << csh) - 1), rt = t >> csh;
    const int r0 = rt * 64, c0 = ct * 64;
    __shared__ float tile[64][65];
    const int tid = threadIdx.x;
    const int lrw = tid >> 4, lcol = (tid & 15) * 4;
    const float* sb = src + (size_t)bz * Rows * Cols + c0;
    #pragma unroll
    for (int p = 0; p < 4; ++p) {
        const int row = p * 16 + lrw;
        float4 v = *(const float4*)(sb + (size_t)(r0 + row) * Cols + lcol);
        tile[row][lcol + 0] = v.x; tile[row][lcol + 1] = v.y;
        tile[row][lcol + 2] = v.z; tile[row][lcol + 3] = v.w;
    }
    __syncthreads();
    if (dm) {
        const int row = tid >> 2, q = tid & 3;
        float s = 0.f;
        #pragma unroll
        for (int j = 0; j < 16; ++j) s += tile[row][q * 16 + j];
        s += __shfl_down(s, 2, 4);
        s += __shfl_down(s, 1, 4);
        if (q == 0) pp[(bz * 16 + ct) * 512 + r0 + row] = s;
    }
    bf16_t* db = dst + (size_t)bz * Rows * Cols + r0;
    #pragma unroll
    for (int q = 0; q < 2; ++q) {
        const int idq = q * 256 + tid;
        const int orow = idq >> 3, seg = idq & 7;
        bf16_t ov[8];
        #pragma unroll
        for (int j = 0; j < 8; ++j) ov[j] = (bf16_t)tile[seg * 8 + j][orow];
        *(bf16x8*)(db + (size_t)(c0 + orow) * Rows + seg * 8) = *(bf16x8*)ov;
    }
}

// ---------- 2. gate ----------
__global__ void gate_kernel(const float* __restrict__ pp, const float* __restrict__ Wg,
                            const float* __restrict__ bg, const float* __restrict__ kmod,
                            int* __restrict__ tidx, float* __restrict__ scale) {
    const int tid = threadIdx.x;           // 512 threads = 8 waves, wave b
    const int b = tid >> 6, l = tid & 63;
    float a[8] = {0.f, 0.f, 0.f, 0.f, 0.f, 0.f, 0.f, 0.f};
    for (int c = l; c < 512; c += 64) {
        float m = 0.f;
        #pragma unroll
        for (int ht = 0; ht < 16; ++ht) m += pp[(b * 16 + ht) * 512 + c];
        #pragma unroll
        for (int e = 0; e < 8; ++e) a[e] += m * Wg[c * 8 + e];
    }
    #pragma unroll
    for (int e = 0; e < 8; ++e)
        #pragma unroll
        for (int off = 32; off; off >>= 1) a[e] += __shfl_xor(a[e], off, 64);
    if (l == 0) {
        float lg[8], mx = -1e30f;
        #pragma unroll
        for (int e = 0; e < 8; ++e) { lg[e] = a[e] * (1.0f / 1024.0f) + bg[e]; mx = fmaxf(mx, lg[e]); }
        float sum = 0.f;
        #pragma unroll
        for (int e = 0; e < 8; ++e) { lg[e] = expf(lg[e] - mx); sum += lg[e]; }
        float inv = 1.0f / sum;
        float best = -1.f; int i0 = 0;
        for (int j = 0; j < 8; ++j) { float w = lg[j] * inv; if (w > best) { best = w; i0 = j; } }
        float best2 = -1.f; int i1 = 0;
        for (int j = 0; j < 8; ++j) { if (j == i0) continue; float w = lg[j] * inv; if (w > best2) { best2 = w; i1 = j; } }
        float kb = kmod[b];
        tidx[b * 2] = i0; tidx[b * 2 + 1] = i1;
        scale[b * 2] = best * kb; scale[b * 2 + 1] = best2 * kb;
    }
}

// ---------- 3. GEMM1: 256x256 tile, BK=32, 512 threads (8 waves 4x2, 64x128 each) ----------
__global__ __launch_bounds__(512, 2) void gemm1_kernel(
    const bf16_t* __restrict__ W1t, const bf16_t* __restrict__ xT,
    const float* __restrict__ b1, const int* __restrict__ tidx,
    const float* __restrict__ scale, bf16_t* __restrict__ hT) {
    __shared__ bf16_t smem[32768];   // 64KB: A @0/8192, B @16384/24576 (256x32 each)
    const int bid = blockIdx.x;
    const int pair = bid >> 4, rem = bid & 15;   // pair = b*2+slot
    const int b = pair >> 1, slot = pair & 1;
    const int e = tidx[pair];
    const float s = scale[pair];
    const int d0 = (rem >> 2) * 256, n0 = (rem & 3) * 256;
    const int tid = threadIdx.x;
    const int lane = tid & 63, wave = tid >> 6;
    const int wm = (wave & 3) * 64, wn = (wave >> 2) * 128;
    const int lrow = lane & 15, quad = lane >> 4;

    const bf16_t* gA = W1t + (size_t)e * 524288 + (size_t)d0 * 512;
    const bf16_t* gB = xT + (size_t)b * 524288 + (size_t)n0 * 512;
    const int srow = tid >> 2, skc = (tid & 3) * 8;   // chunk tid -> rows 0..127

    f32x4 acc[4][8];
    #pragma unroll
    for (int i = 0; i < 4; ++i)
        #pragma unroll
        for (int j = 0; j < 8; ++j) acc[i][j] = (f32x4){0.f, 0.f, 0.f, 0.f};

    auto stage = [&](int st, int k0) {
        bf16_t* dA = smem + st * 8192;
        bf16_t* dB = smem + 16384 + st * 8192;
        GLDS(gA + (size_t)srow * 512 + k0 + skc, dA + tid * 8);
        GLDS(gA + (size_t)(128 + srow) * 512 + k0 + skc, dA + (512 + tid) * 8);
        GLDS(gB + (size_t)srow * 512 + k0 + skc, dB + tid * 8);
        GLDS(gB + (size_t)(128 + srow) * 512 + k0 + skc, dB + (512 + tid) * 8);
    };

    stage(0, 0);
    __syncthreads();

    for (int it = 0; it < 16; ++it) {
        const int cur = it & 1;
        if (it < 15) stage(cur ^ 1, (it + 1) * 32);
        const bf16_t* cA = smem + cur * 8192;
        const bf16_t* cB = smem + 16384 + cur * 8192;
        bf16x8 af[4], bfr[8];
        #pragma unroll
        for (int i = 0; i < 4; ++i)
            af[i] = *(const bf16x8*)&cA[(wm + i * 16 + lrow) * 32 + quad * 8];
        #pragma unroll
        for (int j = 0; j < 8; ++j)
            bfr[j] = *(const bf16x8*)&cB[(wn + j * 16 + lrow) * 32 + quad * 8];
        #pragma unroll
        for (int i = 0; i < 4; ++i)
            #pragma unroll
            for (int j = 0; j < 8; ++j)
                acc[i][j] = __builtin_amdgcn_mfma_f32_16x16x32_bf16(af[i], bfr[j], acc[i][j], 0, 0, 0);
        __syncthreads();
    }

    // epilogue: gelu+bias+scale -> LDS transpose chunks of 64 hw x 256 d -> 16B stores
    bf16_t* hTb = hT + (size_t)b * 2097152 + slot * 1024;
    float4 bb[4];
    #pragma unroll
    for (int i = 0; i < 4; ++i)
        bb[i] = *(const float4*)(b1 + e * 1024 + d0 + wm + i * 16 + quad * 4);

    #pragma unroll
    for (int chk = 0; chk < 4; ++chk) {      // ebuf: [64 hw][264 d] bf16 = 33.8KB
        if ((wn >> 7) == (chk >> 1)) {
            #pragma unroll
            for (int i = 0; i < 4; ++i)
                #pragma unroll
                for (int jj = 0; jj < 4; ++jj) {
                    const int hw_l = jj * 16 + lrow;
                    const int d_l = wm + i * 16 + quad * 4;
                    f32x4 a = acc[i][(chk & 1) * 4 + jj];   // chk unrolled -> static
                    bf16x4 o = { (bf16_t)(gelu_fast(a[0] + bb[i].x) * s),
                                 (bf16_t)(gelu_fast(a[1] + bb[i].y) * s),
                                 (bf16_t)(gelu_fast(a[2] + bb[i].z) * s),
                                 (bf16_t)(gelu_fast(a[3] + bb[i].w) * s) };
                    *(bf16x4*)&smem[hw_l * 264 + d_l] = o;
                }
        }
        __syncthreads();
        #pragma unroll
        for (int q = 0; q < 4; ++q) {
            const int idx = q * 512 + tid;
            const int row = idx >> 5, seg = idx & 31;
            bf16x8 v = *(const bf16x8*)&smem[row * 264 + seg * 8];
            *(bf16x8*)(hTb + (size_t)(n0 + chk * 64 + row) * 2048 + d0 + seg * 8) = v;
        }
        __syncthreads();
    }
}

// ---------- 4. GEMM2: 128x128 tile, BK=64, grid 256; out = x + W2t(sel)@hT + scaled b2 ----------
__global__ __launch_bounds__(256, 2) void gemm2_kernel(
    const bf16_t* __restrict__ W2t, const bf16_t* __restrict__ hT,
    const float* __restrict__ b2, const int* __restrict__ tidx,
    const float* __restrict__ scale, const float* __restrict__ x,
    float* __restrict__ out) {
    __shared__ bf16_t smem[32768];   // 64KB: A @0/8192, B @16384/24576 (128x64 each)
    const int bid = blockIdx.x;
    const int b = bid >> 5, rem = bid & 31;      // grid = 8*32 = 256
    const int c0 = (rem >> 3) * 128, n0 = (rem & 7) * 128;
    const int e0 = tidx[b * 2], e1 = tidx[b * 2 + 1];
    const float s0 = scale[b * 2], s1 = scale[b * 2 + 1];
    const int tid = threadIdx.x;
    const int lane = tid & 63, wave = tid >> 6;
    const int wm = (wave & 1) * 64, wn = (wave >> 1) * 64;
    const int lrow = lane & 15, quad = lane >> 4;

    const bf16_t* hTb = hT + (size_t)b * 2097152 + (size_t)n0 * 2048;
    const bf16_t* A0 = W2t + (size_t)e0 * 524288 + (size_t)c0 * 1024;
    const bf16_t* A1 = W2t + (size_t)e1 * 524288 + (size_t)c0 * 1024;
    const int brow = tid >> 3, bkc = (tid & 7) * 8;   // chunk tid -> 32 rows/pass

    f32x4 acc[4][4];
    #pragma unroll
    for (int i = 0; i < 4; ++i)
        #pragma unroll
        for (int j = 0; j < 4; ++j) acc[i][j] = (f32x4){0.f, 0.f, 0.f, 0.f};

    auto stage = [&](int st, int it) {
        const int k0 = it * 64;                       // never straddles 1024
        const bf16_t* gA = ((k0 < 1024) ? A0 : A1) + (k0 & 1023);
        bf16_t* dA = smem + st * 8192;
        bf16_t* dB = smem + 16384 + st * 8192;
        #pragma unroll
        for (int p = 0; p < 4; ++p) {
            const int row = p * 32 + brow;
            GLDS(gA + (size_t)row * 1024 + bkc, dA + (p * 256 + tid) * 8);
            GLDS(hTb + (size_t)row * 2048 + k0 + bkc, dB + (p * 256 + tid) * 8);
        }
    };

    stage(0, 0);
    __syncthreads();

    for (int it = 0; it < 32; ++it) {
        const int cur = it & 1;
        if (it < 31) stage(cur ^ 1, it + 1);
        const bf16_t* cA = smem + cur * 8192;
        const bf16_t* cB = smem + 16384 + cur * 8192;
        #pragma unroll
        for (int kh = 0; kh < 2; ++kh) {
            bf16x8 af[4], bfr[4];
            #pragma unroll
            for (int i = 0; i < 4; ++i) {
                af[i] = *(const bf16x8*)&cA[(wm + i * 16 + lrow) * 64 + kh * 32 + quad * 8];
                bfr[i] = *(const bf16x8*)&cB[(wn + i * 16 + lrow) * 64 + kh * 32 + quad * 8];
            }
            #pragma unroll
            for (int i = 0; i < 4; ++i)
                #pragma unroll
                for (int j = 0; j < 4; ++j)
                    acc[i][j] = __builtin_amdgcn_mfma_f32_16x16x32_bf16(af[i], bfr[j], acc[i][j], 0, 0, 0);
        }
        __syncthreads();
    }

    #pragma unroll
    for (int i = 0; i < 4; ++i) {
        const int c_l = c0 + wm + i * 16 + quad * 4;
        const float4 bA = *(const float4*)(b2 + e0 * 512 + c_l);
        const float4 bB = *(const float4*)(b2 + e1 * 512 + c_l);
        const float bias[4] = { s0 * bA.x + s1 * bB.x, s0 * bA.y + s1 * bB.y,
                                s0 * bA.z + s1 * bB.z, s0 * bA.w + s1 * bB.w };
        #pragma unroll
        for (int j = 0; j < 4; ++j) {
            const int hw = n0 + wn + j * 16 + lrow;
            #pragma unroll
            for (int r = 0; r < 4; ++r) {
                const size_t o = (size_t)(b * 512 + c_l + r) * 1024 + hw;
                out[o] = x[o] + acc[i][j][r] + bias[r];
            }
        }
    }
}

extern "C" void kernel_launch(void* const* d_in, const int* in_sizes, int n_in,
                              void* d_out, int out_size, void* d_ws, size_t ws_size,
                              hipStream_t stream) {
    const float* x    = (const float*)d_in[0];
    const float* kmod = (const float*)d_in[1];
    const float* Wg   = (const float*)d_in[2];
    const float* bg   = (const float*)d_in[3];
    const float* W1   = (const float*)d_in[4];
    const float* b1   = (const float*)d_in[5];
    const float* W2   = (const float*)d_in[6];
    const float* b2   = (const float*)d_in[7];
    float* out = (float*)d_out;

    char* ws = (char*)d_ws;
    int*   tix  = (int*)ws;
    float* scl  = (float*)(ws + 64);
    bf16_t* xT  = (bf16_t*)(ws + 32768);
    bf16_t* W1t = (bf16_t*)(ws + 32768 + (size_t)8388608);
    bf16_t* W2t = (bf16_t*)(ws + 32768 + (size_t)2 * 8388608);
    bf16_t* hT  = (bf16_t*)(ws + 32768 + (size_t)3 * 8388608);
    float* pp   = (float*)hT;   // gate partials; dead before gemm1 writes hT

    transpose_cvt_all<<<3072, 256, 0, stream>>>(x, W1, W2, xT, W1t, W2t, pp);
    gate_kernel<<<1, 512, 0, stream>>>(pp, Wg, bg, kmod, tix, scl);
    gemm1_kernel<<<256, 512, 0, stream>>>(W1t, xT, b1, tix, scl, hT);    // 16 pairs x 16 tiles
    gemm2_kernel<<<256, 256, 0, stream>>>(W2t, hT, b2, tix, scl, x, out); // 8 x 32 tiles
}

// Round 7
// 174.884 us; speedup vs baseline: 1.0467x; 1.0467x over previous
//
#include <hip/hip_runtime.h>
#include <hip/hip_bf16.h>
#include <math.h>

// MoE top-2 of 8 experts. B=8, C=512, HW=1024, Dh=1024, E=8. fp32 in/out.
// R7: 4 blk/CU everywhere (m114 overlap). XOR-swizzled LDS (kills 8-way frag-read
// conflicts), BK=64 full-128B-line staging, gemm2 operand swap -> coalesced float4
// residual+store (fixes 4B-scatter), gemm1 single-barrier all-wave epilogue.
// Workspace (byte offsets):
//   0      tidx int[16];  64  scale fp32[16]
//   32768  xT  bf16 [8][1024 hw][512 c]
//   +8M    W1t bf16 [8][1024 d][512 c]
//   +16M   W2t bf16 [8][512 c][1024 d]
//   +24M   hT  bf16 [8][1024 hw][2048 slotd]  (pp fp32[8][16][512] aliases hT)

typedef __bf16 bf16_t;
typedef __attribute__((ext_vector_type(8))) __bf16 bf16x8;
typedef __attribute__((ext_vector_type(4))) __bf16 bf16x4;
typedef __attribute__((ext_vector_type(4))) float f32x4;

#define GLDS(g, l) __builtin_amdgcn_global_load_lds(                      \
    (const __attribute__((address_space(1))) void*)(const void*)(g),       \
    (__attribute__((address_space(3))) void*)(void*)(l), 16, 0, 0)

// erf via Abramowitz-Stegun 7.1.26 (validated R2..R6, absmax 0.031)
__device__ __forceinline__ float gelu_fast(float x) {
    float z = x * 0.70710678118654752f;
    float az = fabsf(z);
    float t = 1.0f / (1.0f + 0.3275911f * az);
    float p = ((((1.061405429f * t - 1.453152027f) * t + 1.421413741f) * t
                - 0.284496736f) * t + 0.254829592f) * t;
    float e = __expf(-az * az);
    float er = copysignf(1.0f - p * e, z);
    return 0.5f * x * (1.0f + er);
}

// ---------- 1. coalesced 64x64 transpose+cvt for x/W1/W2 + gate partials (R5-proven) ----------
__global__ __launch_bounds__(256) void transpose_cvt_all(
    const float* __restrict__ x, const float* __restrict__ W1,
    const float* __restrict__ W2, bf16_t* __restrict__ xT,
    bf16_t* __restrict__ W1t, bf16_t* __restrict__ W2t, float* __restrict__ pp) {
    int id = blockIdx.x;
    const float* src; bf16_t* dst; int Rows, Cols, csh; bool dm = false;
    if (id < 1024)      { src = x;  dst = xT;  Rows = 512;  Cols = 1024; csh = 4; dm = true; }
    else if (id < 2048) { id -= 1024; src = W1; dst = W1t; Rows = 512;  Cols = 1024; csh = 4; }
    else                { id -= 2048; src = W2; dst = W2t; Rows = 1024; Cols = 512; csh = 3; }
    const int bz = id >> 7, t = id & 127;
    const int ct = t & ((1 << csh) - 1), rt = t >> csh;
    const int r0 = rt * 64, c0 = ct * 64;
    __shared__ float tile[64][65];
    const int tid = threadIdx.x;
    const int lrw = tid >> 4, lcol = (tid & 15) * 4;
    const float* sb = src + (size_t)bz * Rows * Cols + c0;
    #pragma unroll
    for (int p = 0; p < 4; ++p) {
        const int row = p * 16 + lrw;
        float4 v = *(const float4*)(sb + (size_t)(r0 + row) * Cols + lcol);
        tile[row][lcol + 0] = v.x; tile[row][lcol + 1] = v.y;
        tile[row][lcol + 2] = v.z; tile[row][lcol + 3] = v.w;
    }
    __syncthreads();
    if (dm) {
        const int row = tid >> 2, q = tid & 3;
        float s = 0.f;
        #pragma unroll
        for (int j = 0; j < 16; ++j) s += tile[row][q * 16 + j];
        s += __shfl_down(s, 2, 4);
        s += __shfl_down(s, 1, 4);
        if (q == 0) pp[(bz * 16 + ct) * 512 + r0 + row] = s;
    }
    bf16_t* db = dst + (size_t)bz * Rows * Cols + r0;
    #pragma unroll
    for (int q = 0; q < 2; ++q) {
        const int idq = q * 256 + tid;
        const int orow = idq >> 3, seg = idq & 7;
        bf16_t ov[8];
        #pragma unroll
        for (int j = 0; j < 8; ++j) ov[j] = (bf16_t)tile[seg * 8 + j][orow];
        *(bf16x8*)(db + (size_t)(c0 + orow) * Rows + seg * 8) = *(bf16x8*)ov;
    }
}

// ---------- 2. gate (R5-proven) ----------
__global__ void gate_kernel(const float* __restrict__ pp, const float* __restrict__ Wg,
                            const float* __restrict__ bg, const float* __restrict__ kmod,
                            int* __restrict__ tidx, float* __restrict__ scale) {
    const int tid = threadIdx.x;           // 512 threads = 8 waves, wave b
    const int b = tid >> 6, l = tid & 63;
    float a[8] = {0.f, 0.f, 0.f, 0.f, 0.f, 0.f, 0.f, 0.f};
    for (int c = l; c < 512; c += 64) {
        float m = 0.f;
        #pragma unroll
        for (int ht = 0; ht < 16; ++ht) m += pp[(b * 16 + ht) * 512 + c];
        #pragma unroll
        for (int e = 0; e < 8; ++e) a[e] += m * Wg[c * 8 + e];
    }
    #pragma unroll
    for (int e = 0; e < 8; ++e)
        #pragma unroll
        for (int off = 32; off; off >>= 1) a[e] += __shfl_xor(a[e], off, 64);
    if (l == 0) {
        float lg[8], mx = -1e30f;
        #pragma unroll
        for (int e = 0; e < 8; ++e) { lg[e] = a[e] * (1.0f / 1024.0f) + bg[e]; mx = fmaxf(mx, lg[e]); }
        float sum = 0.f;
        #pragma unroll
        for (int e = 0; e < 8; ++e) { lg[e] = expf(lg[e] - mx); sum += lg[e]; }
        float inv = 1.0f / sum;
        float best = -1.f; int i0 = 0;
        for (int j = 0; j < 8; ++j) { float w = lg[j] * inv; if (w > best) { best = w; i0 = j; } }
        float best2 = -1.f; int i1 = 0;
        for (int j = 0; j < 8; ++j) { if (j == i0) continue; float w = lg[j] * inv; if (w > best2) { best2 = w; i1 = j; } }
        float kb = kmod[b];
        tidx[b * 2] = i0; tidx[b * 2 + 1] = i1;
        scale[b * 2] = best * kb; scale[b * 2 + 1] = best2 * kb;
    }
}

// ---------- 3. GEMM1: 128x128 tile, BK=64, single-buffer, XOR-swizzled LDS ----------
// hT[b][hw][slot*1024+d] = bf16(gelu(W1t[e] @ xT[b] + b1) * scale)
__global__ __launch_bounds__(256, 4) void gemm1_kernel(
    const bf16_t* __restrict__ W1t, const bf16_t* __restrict__ xT,
    const float* __restrict__ b1, const int* __restrict__ tidx,
    const float* __restrict__ scale, bf16_t* __restrict__ hT) {
    __shared__ bf16_t smem[17408];   // stage: A[128x64]@0, B[128x64]@8192; ebuf 128x136
    const int bid = blockIdx.x;
    const int pair = bid >> 6, rem = bid & 63;
    const int b = pair >> 1, slot = pair & 1;
    const int e = tidx[pair];
    const float s = scale[pair];
    const int d0 = (rem >> 3) * 128, n0 = (rem & 7) * 128;
    const int tid = threadIdx.x;
    const int lane = tid & 63, wave = tid >> 6;
    const int wm = (wave & 1) * 64, wn = (wave >> 1) * 64;
    const int lrow = lane & 15, quad = lane >> 4;

    const bf16_t* gA = W1t + (size_t)e * 524288 + (size_t)d0 * 512;
    const bf16_t* gB = xT + (size_t)b * 524288 + (size_t)n0 * 512;

    f32x4 acc[4][4];
    #pragma unroll
    for (int i = 0; i < 4; ++i)
        #pragma unroll
        for (int j = 0; j < 4; ++j) acc[i][j] = (f32x4){0.f, 0.f, 0.f, 0.f};

    for (int it = 0; it < 8; ++it) {
        const int k0 = it * 64;
        // stage: 8 lanes x 16B = full 128B line per row; XOR-swizzle chunk placement
        #pragma unroll
        for (int p = 0; p < 4; ++p) {
            const int row = p * 32 + (tid >> 3);
            const int cg = ((tid & 7) ^ (row & 7)) * 8;
            GLDS(gA + (size_t)row * 512 + k0 + cg, smem + (p * 256 + tid) * 8);
            GLDS(gB + (size_t)row * 512 + k0 + cg, smem + 8192 + (p * 256 + tid) * 8);
        }
        __syncthreads();
        #pragma unroll
        for (int kh = 0; kh < 2; ++kh) {
            const int swz = ((kh * 4 + quad) ^ (lrow & 7)) * 8;
            bf16x8 af[4], bfr[4];
            #pragma unroll
            for (int i = 0; i < 4; ++i) {
                af[i]  = *(const bf16x8*)&smem[(wm + i * 16 + lrow) * 64 + swz];
                bfr[i] = *(const bf16x8*)&smem[8192 + (wn + i * 16 + lrow) * 64 + swz];
            }
            #pragma unroll
            for (int i = 0; i < 4; ++i)
                #pragma unroll
                for (int j = 0; j < 4; ++j)
                    acc[i][j] = __builtin_amdgcn_mfma_f32_16x16x32_bf16(af[i], bfr[j], acc[i][j], 0, 0, 0);
        }
        __syncthreads();
    }

    // epilogue: all waves write all frags (one barrier), then coalesced 16B stores
    bf16_t* hTb = hT + (size_t)b * 2097152 + slot * 1024;
    #pragma unroll
    for (int i = 0; i < 4; ++i) {
        const int d_l = wm + i * 16 + quad * 4;
        const float4 bb = *(const float4*)(b1 + e * 1024 + d0 + d_l);
        #pragma unroll
        for (int j = 0; j < 4; ++j) {
            const int hw_l = wn + j * 16 + lrow;
            f32x4 a = acc[i][j];
            bf16x4 o = { (bf16_t)(gelu_fast(a[0] + bb.x) * s),
                         (bf16_t)(gelu_fast(a[1] + bb.y) * s),
                         (bf16_t)(gelu_fast(a[2] + bb.z) * s),
                         (bf16_t)(gelu_fast(a[3] + bb.w) * s) };
            *(bf16x4*)&smem[hw_l * 136 + d_l] = o;
        }
    }
    __syncthreads();
    #pragma unroll
    for (int q = 0; q < 8; ++q) {
        const int idx = q * 256 + tid;       // 2048 chunks = 128 rows x 16
        const int row = idx >> 4, c16 = idx & 15;
        bf16x8 v = *(const bf16x8*)&smem[row * 136 + c16 * 8];
        *(bf16x8*)(hTb + (size_t)(n0 + row) * 2048 + d0 + c16 * 8) = v;
    }
}

// ---------- 4. GEMM2: operand-swapped (A=hT, B=W2t) -> D[hw][c]; c64 x hw128 tile,
// BK=64, dbuf, grid 512 (2 blk/CU). out = x + D + s0*b2[e0] + s1*b2[e1], float4 stores.
__global__ __launch_bounds__(256, 2) void gemm2_kernel(
    const bf16_t* __restrict__ W2t, const bf16_t* __restrict__ hT,
    const float* __restrict__ b2, const int* __restrict__ tidx,
    const float* __restrict__ scale, const float* __restrict__ x,
    float* __restrict__ out) {
    __shared__ bf16_t smem[24576];   // 2 stages x (A hT[128x64]@0 + B W2t[64x64]@8192)
    const int bid = blockIdx.x;
    const int b = bid >> 6, rem = bid & 63;      // grid = 8 * 64 = 512
    const int c0 = (rem >> 3) * 64, hw0 = (rem & 7) * 128;
    const int e0 = tidx[b * 2], e1 = tidx[b * 2 + 1];
    const float s0 = scale[b * 2], s1 = scale[b * 2 + 1];
    const int tid = threadIdx.x;
    const int lane = tid & 63, wave = tid >> 6;
    const int wm = (wave & 1) * 64;              // hw offset (M)
    const int wc = (wave >> 1) * 32;             // c offset (N)
    const int lrow = lane & 15, quad = lane >> 4;

    const bf16_t* hTb = hT + (size_t)b * 2097152 + (size_t)hw0 * 2048;
    const bf16_t* B0 = W2t + (size_t)e0 * 524288 + (size_t)c0 * 1024;
    const bf16_t* B1 = W2t + (size_t)e1 * 524288 + (size_t)c0 * 1024;

    f32x4 acc[4][2];
    #pragma unroll
    for (int i = 0; i < 4; ++i)
        #pragma unroll
        for (int j = 0; j < 2; ++j) acc[i][j] = (f32x4){0.f, 0.f, 0.f, 0.f};

    auto stage = [&](int st, int it) {
        const int k0 = it * 64;
        bf16_t* dst = smem + st * 12288;
        #pragma unroll
        for (int p = 0; p < 4; ++p) {            // A: hT 128 hw-rows
            const int row = p * 32 + (tid >> 3);
            const int cg = ((tid & 7) ^ (row & 7)) * 8;
            GLDS(hTb + (size_t)row * 2048 + k0 + cg, dst + (p * 256 + tid) * 8);
        }
        const bf16_t* gB = ((it < 16) ? B0 : B1) + (k0 & 1023);
        #pragma unroll
        for (int p = 0; p < 2; ++p) {            // B: W2t 64 c-rows
            const int row = p * 32 + (tid >> 3);
            const int cg = ((tid & 7) ^ (row & 7)) * 8;
            GLDS(gB + (size_t)row * 1024 + cg, dst + 8192 + (p * 256 + tid) * 8);
        }
    };

    stage(0, 0);
    __syncthreads();

    for (int it = 0; it < 32; ++it) {
        const int cur = it & 1;
        if (it < 31) stage(cur ^ 1, it + 1);
        const bf16_t* cA = smem + cur * 12288;
        const bf16_t* cB = cA + 8192;
        #pragma unroll
        for (int kh = 0; kh < 2; ++kh) {
            const int swz = ((kh * 4 + quad) ^ (lrow & 7)) * 8;
            bf16x8 af[4], bfr[2];
            #pragma unroll
            for (int i = 0; i < 4; ++i)
                af[i] = *(const bf16x8*)&cA[(wm + i * 16 + lrow) * 64 + swz];
            #pragma unroll
            for (int j = 0; j < 2; ++j)
                bfr[j] = *(const bf16x8*)&cB[(wc + j * 16 + lrow) * 64 + swz];
            #pragma unroll
            for (int i = 0; i < 4; ++i)
                #pragma unroll
                for (int j = 0; j < 2; ++j)
                    acc[i][j] = __builtin_amdgcn_mfma_f32_16x16x32_bf16(af[i], bfr[j], acc[i][j], 0, 0, 0);
        }
        __syncthreads();
    }

    // epilogue: lane f32x4 = 4 consecutive hw at one c -> fully-coalesced float4
    #pragma unroll
    for (int j = 0; j < 2; ++j) {
        const int c = c0 + wc + j * 16 + lrow;
        const float bias = s0 * b2[e0 * 512 + c] + s1 * b2[e1 * 512 + c];
        #pragma unroll
        for (int i = 0; i < 4; ++i) {
            const int hw = hw0 + wm + i * 16 + quad * 4;
            const size_t o = ((size_t)(b * 512 + c)) * 1024 + hw;
            const float4 xv = *(const float4*)(x + o);
            float4 ov = { acc[i][j][0] + xv.x + bias, acc[i][j][1] + xv.y + bias,
                          acc[i][j][2] + xv.z + bias, acc[i][j][3] + xv.w + bias };
            *(float4*)(out + o) = ov;
        }
    }
}

extern "C" void kernel_launch(void* const* d_in, const int* in_sizes, int n_in,
                              void* d_out, int out_size, void* d_ws, size_t ws_size,
                              hipStream_t stream) {
    const float* x    = (const float*)d_in[0];
    const float* kmod = (const float*)d_in[1];
    const float* Wg   = (const float*)d_in[2];
    const float* bg   = (const float*)d_in[3];
    const float* W1   = (const float*)d_in[4];
    const float* b1   = (const float*)d_in[5];
    const float* W2   = (const float*)d_in[6];
    const float* b2   = (const float*)d_in[7];
    float* out = (float*)d_out;

    char* ws = (char*)d_ws;
    int*   tix  = (int*)ws;
    float* scl  = (float*)(ws + 64);
    bf16_t* xT  = (bf16_t*)(ws + 32768);
    bf16_t* W1t = (bf16_t*)(ws + 32768 + (size_t)8388608);
    bf16_t* W2t = (bf16_t*)(ws + 32768 + (size_t)2 * 8388608);
    bf16_t* hT  = (bf16_t*)(ws + 32768 + (size_t)3 * 8388608);
    float* pp   = (float*)hT;   // gate partials; dead before gemm1 writes hT

    transpose_cvt_all<<<3072, 256, 0, stream>>>(x, W1, W2, xT, W1t, W2t, pp);
    gate_kernel<<<1, 512, 0, stream>>>(pp, Wg, bg, kmod, tix, scl);
    gemm1_kernel<<<1024, 256, 0, stream>>>(W1t, xT, b1, tix, scl, hT);   // 16 pairs x 64
    gemm2_kernel<<<512, 256, 0, stream>>>(W2t, hT, b2, tix, scl, x, out); // 8 x 64
}